// Round 12
// baseline (299.062 us; speedup 1.0000x reference)
//
#include <hip/hip_runtime.h>
#include <hip/hip_fp16.h>

// HiggsMultiLinear: y = x @ W^T + bias, W dequantized from 2-dim VQ codes.
// M=4096 (2x2048), K=4096, N=4096.
// r12 (= r11 re-audited): 256^2 pipelined GEMM, two-barrier-per-phase
// discipline: {reads ; stage ; BAR ; lgkmcnt(0)+SB(0) ; 16 MFMA ; BAR}.
// Barrier-wait absorbs LDS latency; matrix pipe drains across read segments.
// Counted vmcnt(4) before closing BAR of q1/q3 (FIFO proof in comments).

#define M_TOK 4096
#define K_DIM 4096
#define N_DIM 4096
#define NT    (K_DIM / 64)     // 64 K-tiles of BK=64

typedef _Float16 half8 __attribute__((ext_vector_type(8)));
typedef float floatx4 __attribute__((ext_vector_type(4)));

// ---------------------------------------------------------------- dequant W
__global__ void dequant_w(const int* __restrict__ c256, const int* __restrict__ c16,
                          const float* __restrict__ g256, const float* __restrict__ g16,
                          const float* __restrict__ scales,
                          _Float16* __restrict__ Wh)
{
    int idx = blockIdx.x * blockDim.x + threadIdx.x;   // 4 codes per thread
    int row = idx >> 9;                                // (idx*4)/2048 codes per row
    float s = scales[row];
    int4 cd;
    const float* g;
    if (row < 2048) { cd = ((const int4*)c256)[idx]; g = g256; }
    else            { cd = ((const int4*)c16)[idx - (2048*2048/4)]; g = g16; }
    union U { _Float16 h[8]; ulong2 u; } w;
    w.h[0] = (_Float16)(g[2*cd.x]   * s);
    w.h[1] = (_Float16)(g[2*cd.x+1] * s);
    w.h[2] = (_Float16)(g[2*cd.y]   * s);
    w.h[3] = (_Float16)(g[2*cd.y+1] * s);
    w.h[4] = (_Float16)(g[2*cd.z]   * s);
    w.h[5] = (_Float16)(g[2*cd.z+1] * s);
    w.h[6] = (_Float16)(g[2*cd.w]   * s);
    w.h[7] = (_Float16)(g[2*cd.w+1] * s);
    ((ulong2*)Wh)[idx] = w.u;
}

// ---------------------------------------------------------------- cast x
__global__ void cast_x(const float* __restrict__ x, _Float16* __restrict__ xh)
{
    int idx = blockIdx.x * blockDim.x + threadIdx.x;
    float4 v0 = ((const float4*)x)[2*idx];
    float4 v1 = ((const float4*)x)[2*idx + 1];
    union U { _Float16 h[8]; ulong2 u; } o;
    o.h[0] = (_Float16)v0.x; o.h[1] = (_Float16)v0.y;
    o.h[2] = (_Float16)v0.z; o.h[3] = (_Float16)v0.w;
    o.h[4] = (_Float16)v1.x; o.h[5] = (_Float16)v1.y;
    o.h[6] = (_Float16)v1.z; o.h[7] = (_Float16)v1.w;
    ((ulong2*)xh)[idx] = o.u;
}

// ---------------------------------------------------------------- GEMM
__device__ __forceinline__ void gl2lds16(const void* g, void* l)
{
    __builtin_amdgcn_global_load_lds(
        (const __attribute__((address_space(1))) void*)g,
        (__attribute__((address_space(3))) void*)l, 16, 0, 0);
}

// LDS map (halfs): buf*32768 + unit*8192 + cell*8
//   unit: 0=A-kk0, 1=B-kk0, 2=A-kk1, 3=B-kk1  (16 KB each, [R16][kb4][r16][k8])
//   cell(R,kb,r) = R*64 + kb*16 + r ; holds global (row R*16+r, k kb*8..+7)
// Stage: thread t, load L: cell idx=L*512+t (lane-linear LDS dest for gl2lds);
//   global source permuted to match (pre-swizzled-source pattern, m173).
// Phase q of tile tau: reads for q + stage unit q(tau+1) BEFORE the opening
//   barrier; MFMA after (lgkmcnt(0)+sched_barrier(0) per rule 18); closing
//   barrier ends the phase. vmcnt before closing BAR of q1/q3.
// FIFO proof of vmcnt(4) (in loads; 1 unit = 2 loads/thread):
//   invariant at tile entry: 4 outstanding = {u2,u3(tau)}.
//   q0,q1 stage u0,u1(tau+1) -> 8; VMCNT(4) at q1-close retires u2,u3(tau)
//   (guards q2/q3 reads). q2,q3 stage u2,u3(tau+1) -> 8; VMCNT(4) at q3-close
//   retires u0,u1(tau+1) (guards next q0/q1 reads); leaves 4 = invariant.
//   Last tile stages nothing -> VMCNT(0) at both points.
#define STAGE(buf, unit, pan, kcol)                                          \
    { _Float16* lb = &lds[(buf)*32768 + (unit)*8192];                        \
      gl2lds16((pan) + goff0 + (kcol), lb + t*8);                            \
      gl2lds16((pan) + goff1 + (kcol), lb + (512+t)*8); }

#define RD_A(q, mm) (*(const half8*)&lds[cur*32768 + ((q)>>1)*2*8192 +       \
      ((wr*8 + ((q)&1)*4 + (mm))*64 + kbr*16 + lrow)*8])
#define RD_B(q, n)  (*(const half8*)&lds[cur*32768 + (((q)>>1)*2+1)*8192 +   \
      ((wc*4 + (n))*64 + kbr*16 + lrow)*8])

#define PHASE_MFMA(q)                                                        \
    __builtin_amdgcn_s_setprio(1);                                           \
    _Pragma("unroll")                                                        \
    for (int mm = 0; mm < 4; ++mm) {                                         \
        _Pragma("unroll")                                                    \
        for (int n = 0; n < 4; ++n)                                          \
            acc[((q)&1)*4+mm][n] = __builtin_amdgcn_mfma_f32_16x16x32_f16(   \
                a[mm], b[n], acc[((q)&1)*4+mm][n], 0, 0, 0);                 \
    }                                                                        \
    __builtin_amdgcn_s_setprio(0);

// opening barrier + data fence for this phase's MFMAs (rule 18 fence)
#define OPEN_MFMA()                                                          \
    __builtin_amdgcn_s_barrier();                                            \
    asm volatile("s_waitcnt lgkmcnt(0)" ::: "memory");                       \
    __builtin_amdgcn_sched_barrier(0);

#define VMCNT(morev)                                                         \
    if (morev) asm volatile("s_waitcnt vmcnt(4)" ::: "memory");              \
    else       asm volatile("s_waitcnt vmcnt(0)" ::: "memory");

__global__ __launch_bounds__(512, 2)
void gemm8p(const _Float16* __restrict__ Xh, const _Float16* __restrict__ Wh,
            const float* __restrict__ bias, float* __restrict__ C)
{
    extern __shared__ _Float16 lds[];   // 128 KB

    const int t    = threadIdx.x;
    const int lane = t & 63;
    const int w    = t >> 6;
    const int wr   = w >> 2;           // 0..1  (M-half of block tile)
    const int wc   = w & 3;            // 0..3  (N-quarter)
    const int lrow = lane & 15;
    const int kbr  = lane >> 4;        // k-octet 0..3

    // XCD-aware bijective swizzle: 256 blocks, 8 XCDs -> 32 contiguous each.
    const int swz  = (blockIdx.x & 7) * 32 + (blockIdx.x >> 3);
    const int bx   = swz & 15;
    const int by   = swz >> 4;
    const int brow = by * 256;
    const int bcol = bx * 256;

    // stage decode per load L (lane-constant across tiles)
    const int idx0 = t,        idx1 = 512 + t;
    const size_t goff0 = (size_t)((idx0 >> 6)*16 + (idx0 & 15)) * K_DIM + ((idx0 >> 4) & 3)*8;
    const size_t goff1 = (size_t)((idx1 >> 6)*16 + (idx1 & 15)) * K_DIM + ((idx1 >> 4) & 3)*8;

    const _Float16* Apan = Xh + (size_t)brow * K_DIM;
    const _Float16* Bpan = Wh + (size_t)bcol * K_DIM;

    floatx4 acc[8][4];
    #pragma unroll
    for (int m = 0; m < 8; ++m)
        #pragma unroll
        for (int n = 0; n < 4; ++n)
            #pragma unroll
            for (int r = 0; r < 4; ++r) acc[m][n][r] = 0.0f;

    // prologue: stage all 4 units of tile 0 (8 loads/thread); u0,u1 must land
    STAGE(0, 0, Apan, 0);
    STAGE(0, 1, Bpan, 0);
    STAGE(0, 2, Apan, 32);
    STAGE(0, 3, Bpan, 32);
    asm volatile("s_waitcnt vmcnt(4)" ::: "memory");
    __builtin_amdgcn_s_barrier();

    for (int tau = 0; tau < NT; ++tau) {
        const int  cur  = tau & 1;
        const int  nxt  = cur ^ 1;
        const int  kn   = (tau + 1) * 64;
        const bool more = (tau + 1 < NT);
        half8 a[4], b[4];

        // ---- q0: kk0, sub-half 0
        #pragma unroll
        for (int n = 0; n < 4; ++n)  b[n] = RD_B(0, n);
        #pragma unroll
        for (int mm = 0; mm < 4; ++mm) a[mm] = RD_A(0, mm);
        if (more) STAGE(nxt, 0, Apan, kn);
        OPEN_MFMA();
        PHASE_MFMA(0);
        __builtin_amdgcn_s_barrier();

        // ---- q1: kk0, sub-half 1 (B reused)
        #pragma unroll
        for (int mm = 0; mm < 4; ++mm) a[mm] = RD_A(1, mm);
        if (more) STAGE(nxt, 1, Bpan, kn);
        OPEN_MFMA();
        PHASE_MFMA(1);
        VMCNT(more);                  // retires u2,u3(tau) -> guards q2 reads
        __builtin_amdgcn_s_barrier();

        // ---- q2: kk1, sub-half 0
        #pragma unroll
        for (int n = 0; n < 4; ++n)  b[n] = RD_B(2, n);
        #pragma unroll
        for (int mm = 0; mm < 4; ++mm) a[mm] = RD_A(2, mm);
        if (more) STAGE(nxt, 2, Apan, kn + 32);
        OPEN_MFMA();
        PHASE_MFMA(2);
        __builtin_amdgcn_s_barrier();

        // ---- q3: kk1, sub-half 1 (B reused)
        #pragma unroll
        for (int mm = 0; mm < 4; ++mm) a[mm] = RD_A(3, mm);
        if (more) STAGE(nxt, 3, Bpan, kn + 32);
        OPEN_MFMA();
        PHASE_MFMA(3);
        VMCNT(more);                  // retires u0,u1(tau+1) -> guards next q0
        __builtin_amdgcn_s_barrier();
    }

    // epilogue: C[row][col] = acc + bias[col]
    #pragma unroll
    for (int n = 0; n < 4; ++n) {
        const int col = bcol + wc*64 + n*16 + lrow;
        const float bv = bias[col];
        #pragma unroll
        for (int m = 0; m < 8; ++m) {
            const int rbase = brow + wr*128 + m*16 + kbr*4;
            #pragma unroll
            for (int r = 0; r < 4; ++r)
                C[(size_t)(rbase + r) * N_DIM + col] = acc[m][n][r] + bv;
        }
    }
}

// ---------------------------------------------------------------- launch
extern "C" void kernel_launch(void* const* d_in, const int* in_sizes, int n_in,
                              void* d_out, int out_size, void* d_ws, size_t ws_size,
                              hipStream_t stream)
{
    const float* x      = (const float*)d_in[0];
    const int*   c256   = (const int*)  d_in[1];
    const int*   c16    = (const int*)  d_in[2];
    const float* g256   = (const float*)d_in[3];
    const float* g16    = (const float*)d_in[4];
    const float* scales = (const float*)d_in[5];
    const float* bias   = (const float*)d_in[6];
    float*       out    = (float*)d_out;

    char* ws = (char*)d_ws;
    const size_t SZ = (size_t)K_DIM * N_DIM * sizeof(_Float16);  // 32 MB
    _Float16* Wh = (_Float16*)(ws + 0*SZ);
    _Float16* Xh = (_Float16*)(ws + 1*SZ);

    // allow 128 KB dynamic LDS (host-side attribute set, capture-safe,
    // idempotent -> same work every call; proven in r10's pass)
    hipFuncSetAttribute((const void*)gemm8p,
                        hipFuncAttributeMaxDynamicSharedMemorySize, 131072);

    dequant_w<<<dim3((4096*2048/4)/256), dim3(256), 0, stream>>>(
        c256, c16, g256, g16, scales, Wh);
    cast_x<<<dim3((M_TOK*K_DIM/8)/256), dim3(256), 0, stream>>>(x, Xh);
    // 256 blocks (16x16 tiles of 256x256), 512 threads, 128 KB LDS
    gemm8p<<<dim3(256), dim3(512), 131072, stream>>>(Xh, Wh, bias, out);
}